// Round 1
// baseline (45.876 us; speedup 1.0000x reference)
//
#include <hip/hip_runtime.h>
#include <hip/hip_bf16.h>

// MultiScaleRoIAlign for FPN:
//   feats: stride {4,8,16,32} -> shapes (2,256,256,256)/(2,256,128,128)/(2,256,64,64)/(2,256,32,32) f32 NCHW
//   boxes: (2,256,4) xyxy in image coords (IMG=1024)
//   out:   (512, 256, 7, 7) f32
// Level select: lvl = clip(floor(4 + log2(sqrt(area)/224 + 1e-8)), 2, 5) - 2
// ROI align: 1 bilinear sample per bin at bin center, ALIGNED=False (offset 0),
// roi w/h clamped to >= 1, validity mask (s > -1 && s < H) else 0.

#define RLANES 256   // threads per block
#define C_DIM 256
#define OUTB 7
#define NBINS 49     // 7*7
#define PER_ROI (C_DIM * NBINS)  // 12544 = 49 blocks of 256

__global__ __launch_bounds__(RLANES) void msroi_kernel(
    const float* __restrict__ f0, const float* __restrict__ f1,
    const float* __restrict__ f2, const float* __restrict__ f3,
    const float* __restrict__ boxes, float* __restrict__ out) {
  const int r   = blockIdx.x / NBINS;        // ROI index 0..511 (uniform per block)
  const int blk = blockIdx.x - r * NBINS;    // chunk within ROI
  const int le  = blk * RLANES + threadIdx.x; // 0..12543 within ROI
  const int c   = le / NBINS;
  const int bin = le - c * NBINS;
  const int py  = bin / OUTB;
  const int px  = bin - py * OUTB;

  const int n = r >> 8;  // L = 256 rois per image

  const float4 box = ((const float4*)boxes)[r];

  // ---- level selection (exactly as reference) ----
  float bw = fmaxf(box.z - box.x, 0.0f);
  float bh = fmaxf(box.w - box.y, 0.0f);
  float area = bw * bh;
  float lv = floorf(4.0f + log2f(sqrtf(area) / 224.0f + 1e-8f));
  int lvl = (int)(fminf(fmaxf(lv, 2.0f), 5.0f)) - 2;  // 0..3

  const float* __restrict__ feat;
  int H; float scale;
  switch (lvl) {
    case 0:  feat = f0; H = 256; scale = 0.25f;    break;
    case 1:  feat = f1; H = 128; scale = 0.125f;   break;
    case 2:  feat = f2; H = 64;  scale = 0.0625f;  break;
    default: feat = f3; H = 32;  scale = 0.03125f; break;
  }
  const int W = H;

  // ---- ROI geometry ----
  const float x1 = box.x * scale, y1 = box.y * scale;
  const float x2 = box.z * scale, y2 = box.w * scale;
  const float roi_w = fmaxf(x2 - x1, 1.0f);
  const float roi_h = fmaxf(y2 - y1, 1.0f);
  const float bin_w = roi_w / (float)OUTB;
  const float bin_h = roi_h / (float)OUTB;

  // Boundary-sensitive: keep separate rounding (no fma contraction) to match
  // the numpy reference's (grid*bin) then (+origin) float32 rounding for the
  // validity-mask comparisons.
  const float gy = (float)py + 0.5f;
  const float gx = (float)px + 0.5f;
  const float ysf = __fadd_rn(y1, __fmul_rn(gy, bin_h));
  const float xsf = __fadd_rn(x1, __fmul_rn(gx, bin_w));

  const bool vy = (ysf > -1.0f) && (ysf < (float)H);
  const bool vx = (xsf > -1.0f) && (xsf < (float)W);

  float y = fminf(fmaxf(ysf, 0.0f), (float)(H - 1));
  float x = fminf(fmaxf(xsf, 0.0f), (float)(W - 1));
  int y0 = min((int)floorf(y), H - 2);
  int x0 = min((int)floorf(x), W - 2);
  const float ly = y - (float)y0;
  const float lx = x - (float)x0;

  const float* __restrict__ p =
      feat + (((size_t)n * C_DIM + c) * (size_t)H + y0) * (size_t)W + x0;
  const float v00 = p[0];
  const float v01 = p[1];
  const float v10 = p[W];
  const float v11 = p[W + 1];

  float val = (1.0f - ly) * ((1.0f - lx) * v00 + lx * v01) +
              ly * ((1.0f - lx) * v10 + lx * v11);
  val = (vy && vx) ? val : 0.0f;

  out[(size_t)r * PER_ROI + le] = val;
}

extern "C" void kernel_launch(void* const* d_in, const int* in_sizes, int n_in,
                              void* d_out, int out_size, void* d_ws, size_t ws_size,
                              hipStream_t stream) {
  const float* f0 = (const float*)d_in[0];
  const float* f1 = (const float*)d_in[1];
  const float* f2 = (const float*)d_in[2];
  const float* f3 = (const float*)d_in[3];
  const float* boxes = (const float*)d_in[4];
  float* out = (float*)d_out;

  const int R = 512;  // N*L = 2*256
  dim3 grid(R * NBINS);
  dim3 block(RLANES);
  msroi_kernel<<<grid, block, 0, stream>>>(f0, f1, f2, f3, boxes, out);
}

// Round 2
// 43.150 us; speedup vs baseline: 1.0632x; 1.0632x over previous
//
#include <hip/hip_runtime.h>
#include <hip/hip_bf16.h>

// MultiScaleRoIAlign for FPN:
//   feats: stride {4,8,16,32} -> (2,256,256,256)/(2,256,128,128)/(2,256,64,64)/(2,256,32,32) f32 NCHW
//   boxes: (2,256,4) xyxy, IMG=1024
//   out:   (512, 256, 7, 7) f32
// Level select: lvl = clip(floor(4 + log2(sqrt(area)/224 + 1e-8)), 2, 5) - 2
// 1 bilinear sample per bin at bin center, ALIGNED=False, roi w/h >= 1,
// validity mask (s > -1 && s < H) else 0.

#define RLANES 256   // threads per block
#define C_DIM 256
#define OUTB 7
#define NBINS 49     // 7*7
#define PER_ROI (C_DIM * NBINS)  // 12544 = 49 blocks of 256
#define NROI 512
#define NXCD 8
#define ROI_PER_XCD (NROI / NXCD)  // 64

__global__ __launch_bounds__(RLANES) void msroi_kernel(
    const float* __restrict__ f0, const float* __restrict__ f1,
    const float* __restrict__ f2, const float* __restrict__ f3,
    const float* __restrict__ boxes, float* __restrict__ out) {
  // XCD swizzle: 25088 blocks = 8 XCDs x 3136. Consecutive blockIdx round-robin
  // XCDs, so give XCD k the rois [64k, 64k+64): all 49 blocks of a roi land on
  // one XCD's L2 (one fetch of the roi's window set instead of up to 8).
  const int wg   = blockIdx.x;
  const int xcd  = wg & (NXCD - 1);
  const int slot = wg >> 3;              // 0..3135
  const int rr   = slot / NBINS;         // 0..63
  const int blk  = slot - rr * NBINS;    // 0..48
  const int r    = xcd * ROI_PER_XCD + rr;

  const int le  = blk * RLANES + threadIdx.x; // 0..12543 within ROI
  const int c   = le / NBINS;
  const int bin = le - c * NBINS;
  const int py  = bin / OUTB;
  const int px  = bin - py * OUTB;

  const int n = r >> 8;  // L = 256 rois per image

  const float4 box = ((const float4*)boxes)[r];

  // ---- level selection (exactly as reference) ----
  float bw = fmaxf(box.z - box.x, 0.0f);
  float bh = fmaxf(box.w - box.y, 0.0f);
  float area = bw * bh;
  float lv = floorf(4.0f + log2f(sqrtf(area) / 224.0f + 1e-8f));
  int lvl = (int)(fminf(fmaxf(lv, 2.0f), 5.0f)) - 2;  // 0..3

  const float* __restrict__ feat;
  int H; float scale;
  switch (lvl) {
    case 0:  feat = f0; H = 256; scale = 0.25f;    break;
    case 1:  feat = f1; H = 128; scale = 0.125f;   break;
    case 2:  feat = f2; H = 64;  scale = 0.0625f;  break;
    default: feat = f3; H = 32;  scale = 0.03125f; break;
  }
  const int W = H;

  // ---- ROI geometry ----
  const float x1 = box.x * scale, y1 = box.y * scale;
  const float x2 = box.z * scale, y2 = box.w * scale;
  const float roi_w = fmaxf(x2 - x1, 1.0f);
  const float roi_h = fmaxf(y2 - y1, 1.0f);
  const float bin_w = roi_w / (float)OUTB;
  const float bin_h = roi_h / (float)OUTB;

  // Boundary-sensitive: separate rounding (no fma contraction) to match the
  // numpy reference for the validity-mask comparisons.
  const float gy = (float)py + 0.5f;
  const float gx = (float)px + 0.5f;
  const float ysf = __fadd_rn(y1, __fmul_rn(gy, bin_h));
  const float xsf = __fadd_rn(x1, __fmul_rn(gx, bin_w));

  const bool vy = (ysf > -1.0f) && (ysf < (float)H);
  const bool vx = (xsf > -1.0f) && (xsf < (float)W);

  float y = fminf(fmaxf(ysf, 0.0f), (float)(H - 1));
  float x = fminf(fmaxf(xsf, 0.0f), (float)(W - 1));
  int y0 = min((int)floorf(y), H - 2);
  int x0 = min((int)floorf(x), W - 2);
  const float ly = y - (float)y0;
  const float lx = x - (float)x0;

  const float* __restrict__ p =
      feat + (((size_t)n * C_DIM + c) * (size_t)H + y0) * (size_t)W + x0;
  // Row-pair vector gathers: (v00,v01) and (v10,v11) are contiguous -> one
  // 8B gather each (CDNA global loads handle unaligned addresses).
  const float2 v0 = *reinterpret_cast<const float2*>(p);
  const float2 v1 = *reinterpret_cast<const float2*>(p + W);

  const float wx0 = 1.0f - lx;
  float val = (1.0f - ly) * (wx0 * v0.x + lx * v0.y) +
              ly * (wx0 * v1.x + lx * v1.y);
  val = (vy && vx) ? val : 0.0f;

  out[(size_t)r * PER_ROI + le] = val;
}

extern "C" void kernel_launch(void* const* d_in, const int* in_sizes, int n_in,
                              void* d_out, int out_size, void* d_ws, size_t ws_size,
                              hipStream_t stream) {
  const float* f0 = (const float*)d_in[0];
  const float* f1 = (const float*)d_in[1];
  const float* f2 = (const float*)d_in[2];
  const float* f3 = (const float*)d_in[3];
  const float* boxes = (const float*)d_in[4];
  float* out = (float*)d_out;

  dim3 grid(NROI * NBINS);
  dim3 block(RLANES);
  msroi_kernel<<<grid, block, 0, stream>>>(f0, f1, f2, f3, boxes, out);
}